// Round 12
// baseline (61.862 us; speedup 1.0000x reference)
//
#include <hip/hip_runtime.h>

#define H_STEPS 200
#define DT 0.01f
#define K_SPRING 100.0f
#define NQH 25   // 25 float4 = half a row per lane

__device__ __forceinline__ void step(float u, float& x1, float& v1,
                                     float& x2, float& v2) {
    float pen     = x1 + 1.0f - x2;
    float contact = fmaxf(pen, 0.0f);
    float Fc      = -K_SPRING * contact;
    float F1      = u + Fc - v1;      // C = 1
    float F2      = -Fc - v2;
    v1 += F1 * DT;
    v2 += F2 * DT;
    x1 += v1 * DT;
    x2 += v2 * DT;
}

__device__ __forceinline__ float4 shfl_partner(float4 v) {
    float4 r;
    r.x = __shfl_xor(v.x, 1);
    r.y = __shfl_xor(v.y, 1);
    r.z = __shfl_xor(v.z, 1);
    r.w = __shfl_xor(v.w, 1);
    return r;
}

// Occupancy experiment: 2 lanes per row. Both lanes of a pair run the serial
// recurrence REDUNDANTLY (compute is ~10x cheaper than memory); each lane
// loads only half the row (even: qwords 0..24, odd: 25..49), halves exchanged
// at use time via __shfl_xor(.,1) (neighbor DPP swap). Work per wave halves ->
// 4096 waves = 16 waves/CU (vs the 8 that every previous ~24us variant had).
// Tests whether the 4.5 TB/s plateau is latency-hiding (occupancy) capped.
__global__ __launch_bounds__(256, 4)   // 4 waves/EU -> <=128 VGPR
void pushing_env_kernel(const float* __restrict__ u_seq,
                        const float* __restrict__ x1_0,
                        const float* __restrict__ v1_0,
                        const float* __restrict__ x2_0,
                        const float* __restrict__ v2_0,
                        const float* __restrict__ goal,
                        float* __restrict__ out, int B) {
    const int tid  = threadIdx.x;
    const int half = tid & 1;                          // 0: qwords 0-24, 1: 25-49
    const int b    = blockIdx.x * 128 + (tid >> 1);    // row (shared by pair)

    float x1 = x1_0[b];
    float v1 = v1_0[b];
    float x2 = x2_0[b];
    float v2 = v2_0[b];
    const float g = goal[0];

    const float4* u = reinterpret_cast<const float4*>(u_seq + (size_t)b * H_STEPS);

    // Each lane prefetches its 25-qword half (array form: R3's proven-fast
    // compiler-scheduled deep pipeline; static indices after unroll).
    float4 r[NQH];
    #pragma unroll
    for (int q = 0; q < NQH; ++q)
        r[q] = u[half * NQH + q];

    // Steps 0..99: data lives in even lane (its r[q] is qword q).
    #pragma unroll
    for (int q = 0; q < NQH; ++q) {
        float4 p = shfl_partner(r[q]);
        float4 u4 = half ? p : r[q];
        step(u4.x, x1, v1, x2, v2);
        step(u4.y, x1, v1, x2, v2);
        step(u4.z, x1, v1, x2, v2);
        step(u4.w, x1, v1, x2, v2);
    }
    // Steps 100..199: data lives in odd lane (its r[q] is qword 25+q).
    #pragma unroll
    for (int q = 0; q < NQH; ++q) {
        float4 p = shfl_partner(r[q]);
        float4 u4 = half ? r[q] : p;
        step(u4.x, x1, v1, x2, v2);
        step(u4.y, x1, v1, x2, v2);
        step(u4.z, x1, v1, x2, v2);
        step(u4.w, x1, v1, x2, v2);
    }

    if (half == 0) {            // pair results identical; even lane stores
        float d = x2 - g;
        out[b]         = d * d; // loss
        out[B + b]     = x1;
        out[2 * B + b] = x2;
    }
}

extern "C" void kernel_launch(void* const* d_in, const int* in_sizes, int n_in,
                              void* d_out, int out_size, void* d_ws, size_t ws_size,
                              hipStream_t stream) {
    const float* u_seq = (const float*)d_in[0];
    const float* x1_0  = (const float*)d_in[1];
    const float* v1_0  = (const float*)d_in[2];
    const float* x2_0  = (const float*)d_in[3];
    const float* v2_0  = (const float*)d_in[4];
    const float* goal  = (const float*)d_in[5];
    float* out = (float*)d_out;
    (void)d_ws; (void)ws_size;

    const int B = in_sizes[1];   // 131072
    const int grid = B / 128;    // 1024 blocks x 256 thr; 2 lanes per row
    pushing_env_kernel<<<grid, 256, 0, stream>>>(u_seq, x1_0, v1_0, x2_0,
                                                 v2_0, goal, out, B);
}